// Round 2
// baseline (531.613 us; speedup 1.0000x reference)
//
#include <hip/hip_runtime.h>
#include <hip/hip_bf16.h>
#include <math.h>

#define NB 32
#define NS 4096
#define ND 512
#define NU 128
#define RR 32
#define NCHUNK (NS / RR)   // 128

typedef __bf16 bf16x8 __attribute__((ext_vector_type(8)));
typedef unsigned short u16x8 __attribute__((ext_vector_type(8)));
typedef float f32x4 __attribute__((ext_vector_type(4)));
union FragCvt { u16x8 u; bf16x8 b; };

__device__ inline unsigned short f2bf(float x) {
  union { float f; unsigned u; } v; v.f = x;
  return (unsigned short)((v.u + 0x7FFFu + ((v.u >> 16) & 1u)) >> 16);
}

__device__ inline u16x8 pack8(float4 a, float4 b) {
  u16x8 r;
  r[0] = f2bf(a.x); r[1] = f2bf(a.y); r[2] = f2bf(a.z); r[3] = f2bf(a.w);
  r[4] = f2bf(b.x); r[5] = f2bf(b.y); r[6] = f2bf(b.z); r[7] = f2bf(b.w);
  return r;
}

// ---- prep: qb[b][u] = q@W1 + b1 + b2 ; w2t[u][d] = bf16(W2[d][u]) ----
__global__ void prep(const float* __restrict__ q, const float* __restrict__ W1,
                     const float* __restrict__ b1, const float* __restrict__ b2,
                     const float* __restrict__ W2,
                     float* __restrict__ qb, unsigned short* __restrict__ w2t) {
  if (blockIdx.x < 16) {
    int idx = blockIdx.x * 256 + threadIdx.x;    // 4096 = 32*128
    int b = idx >> 7, u = idx & 127;
    float s = b1[u] + b2[u];
    const float* qr = q + b * ND;
    #pragma unroll 8
    for (int d = 0; d < ND; ++d) s += qr[d] * W1[d * NU + u];
    qb[idx] = s;
  } else {
    int idx = (blockIdx.x - 16) * 256 + threadIdx.x;  // 65536 = 128*512
    int u = idx >> 9, d = idx & 511;
    w2t[idx] = f2bf(W2[d * NU + u]);
  }
}

// ---- fused: barrier-free MFMA K-loop (B in VGPRs, A straight from global) ----
__global__ __launch_bounds__(512, 4) void fused_attn(
    const float* __restrict__ values,
    const float* __restrict__ qb,            // [NB][NU]
    const unsigned short* __restrict__ w2t,  // [NU][ND] bf16 bits
    const float* __restrict__ V,             // [NU]
    const float* __restrict__ bvp,           // [1]
    float* __restrict__ wout,                // [NB][NS] unnormalized e^s
    float* __restrict__ Cpart,               // [NB*NCHUNK][ND] per-block context partials
    float* __restrict__ Lacc)                // [NB] denom (zeroed)
{
  __shared__ float cbuf[4][16][64];   // K-half combine: 16 KB
  __shared__ float sbuf[4][32];       // per-ngroup row scores
  __shared__ float wlds[32];          // e^s per row

  const int tid = threadIdx.x;
  const int b = blockIdx.x >> 7;
  const int chunk = blockIdx.x & 127;
  const int s0 = chunk * RR;
  const int wave = tid >> 6, lane = tid & 63;
  const int quad = lane >> 4, lidx = lane & 15;
  const int khalf = wave & 1, ng = wave >> 1;   // K-half, n-group (2 n-tiles each)

  const float* vbase = values + ((size_t)b * NS + s0) * ND;

  // B fragments: loaded once per block from L2-resident w2t. 64 VGPRs.
  FragCvt bfr[2][8];
  #pragma unroll
  for (int nt = 0; nt < 2; ++nt) {
    const int u = ng * 32 + nt * 16 + lidx;
    #pragma unroll
    for (int k8 = 0; k8 < 8; ++k8)
      bfr[nt][k8].u = *(const u16x8*)(w2t + u * ND + (khalf * 8 + k8) * 32 + quad * 8);
  }

  f32x4 acc[2][2];
  #pragma unroll
  for (int mt = 0; mt < 2; ++mt)
    #pragma unroll
    for (int nt = 0; nt < 2; ++nt)
      acc[mt][nt] = (f32x4){0.f, 0.f, 0.f, 0.f};

  // K-loop: no barriers, no LDS. A frag = 8 contiguous fp32 per lane.
  #pragma unroll
  for (int k8 = 0; k8 < 8; ++k8) {
    const int kc = (khalf * 8 + k8) * 32 + quad * 8;
    #pragma unroll
    for (int mt = 0; mt < 2; ++mt) {
      const float* ap = vbase + (mt * 16 + lidx) * ND + kc;
      float4 a0 = *(const float4*)ap;
      float4 a1 = *(const float4*)(ap + 4);
      FragCvt af; af.u = pack8(a0, a1);
      #pragma unroll
      for (int nt = 0; nt < 2; ++nt)
        acc[mt][nt] = __builtin_amdgcn_mfma_f32_16x16x32_bf16(af.b, bfr[nt][k8].b, acc[mt][nt], 0, 0, 0);
    }
  }

  // ---- combine K halves: khalf=1 waves dump acc, khalf=0 waves add ----
  if (khalf == 1) {
    #pragma unroll
    for (int mt = 0; mt < 2; ++mt)
      #pragma unroll
      for (int nt = 0; nt < 2; ++nt)
        #pragma unroll
        for (int r = 0; r < 4; ++r)
          cbuf[ng][mt * 8 + nt * 4 + r][lane] = acc[mt][nt][r];
  }
  __syncthreads();

  if (khalf == 0) {
    float part[2][4] = {{0.f,0.f,0.f,0.f},{0.f,0.f,0.f,0.f}};
    #pragma unroll
    for (int mt = 0; mt < 2; ++mt) {
      #pragma unroll
      for (int nt = 0; nt < 2; ++nt) {
        const int col = ng * 32 + nt * 16 + lidx;
        const float qv = qb[b * NU + col];
        const float vv = V[col];
        #pragma unroll
        for (int r = 0; r < 4; ++r) {
          float full = acc[mt][nt][r] + cbuf[ng][mt * 8 + nt * 4 + r][lane];
          part[mt][r] += tanhf(full + qv) * vv;
        }
      }
    }
    #pragma unroll
    for (int m = 1; m <= 8; m <<= 1)
      #pragma unroll
      for (int mt = 0; mt < 2; ++mt)
        #pragma unroll
        for (int r = 0; r < 4; ++r)
          part[mt][r] += __shfl_xor(part[mt][r], m, 64);
    if (lidx == 0) {
      #pragma unroll
      for (int mt = 0; mt < 2; ++mt)
        #pragma unroll
        for (int r = 0; r < 4; ++r)
          sbuf[ng][mt * 16 + quad * 4 + r] = part[mt][r];
    }
  }
  __syncthreads();

  if (tid < 32) {
    float s = sbuf[0][tid] + sbuf[1][tid] + sbuf[2][tid] + sbuf[3][tid];
    float e = expf(s + *bvp);               // scores bounded by ||V||_1 -> no max pass
    wout[(size_t)b * NS + s0 + tid] = e;
    wlds[tid] = e;
    float es = e;
    #pragma unroll
    for (int m = 1; m <= 16; m <<= 1) es += __shfl_xor(es, m, 64);
    if (tid == 0) atomicAdd(Lacc + b, es);
  }
  __syncthreads();

  // ---- context partial: one d-column per thread, fp32 values from L2 ----
  float c = 0.f;
  #pragma unroll 8
  for (int r = 0; r < RR; ++r)
    c += wlds[r] * vbase[r * ND + tid];
  Cpart[(size_t)blockIdx.x * ND + tid] = c;
}

// ---- finalize: tree-reduce context partials + normalize weights ----
__global__ void finalize(const float* __restrict__ Cpart, const float* __restrict__ Lacc,
                         float* __restrict__ out) {
  int idx = blockIdx.x * 256 + threadIdx.x;   // 147456 total
  if (idx < NB * ND) {
    int b = idx >> 9, d = idx & 511;
    const float* p = Cpart + (size_t)b * NCHUNK * ND + d;
    float a0 = 0.f, a1 = 0.f, a2 = 0.f, a3 = 0.f;
    #pragma unroll 4
    for (int c = 0; c < NCHUNK; c += 4) {
      a0 += p[(size_t)(c + 0) * ND];
      a1 += p[(size_t)(c + 1) * ND];
      a2 += p[(size_t)(c + 2) * ND];
      a3 += p[(size_t)(c + 3) * ND];
    }
    out[idx] = (a0 + a1 + a2 + a3) / Lacc[b];
  } else {
    int j = idx - NB * ND;
    int b = j >> 12;
    out[idx] = out[idx] / Lacc[b];
  }
}

extern "C" void kernel_launch(void* const* d_in, const int* in_sizes, int n_in,
                              void* d_out, int out_size, void* d_ws, size_t ws_size,
                              hipStream_t stream) {
  const float* query  = (const float*)d_in[0];
  const float* values = (const float*)d_in[1];
  const float* W1     = (const float*)d_in[2];
  const float* b1     = (const float*)d_in[3];
  const float* W2     = (const float*)d_in[4];
  const float* b2     = (const float*)d_in[5];
  const float* V      = (const float*)d_in[6];
  const float* bv     = (const float*)d_in[7];
  float* out = (float*)d_out;

  char* ws = (char*)d_ws;
  float* Cpart = (float*)ws;                                   // 4096*512*4 = 8 MB
  float* Lacc  = (float*)(ws + 8388608);                       // 128 B
  float* qbuf  = (float*)(ws + 8389120);                       // 16 KB
  unsigned short* w2t = (unsigned short*)(ws + 8405504);       // 128 KB

  hipMemsetAsync(Lacc, 0, 512, stream);

  prep<<<272, 256, 0, stream>>>(query, W1, b1, b2, W2, qbuf, w2t);
  fused_attn<<<NB * NCHUNK, 512, 0, stream>>>(values, qbuf, w2t, V, bv,
                                              out + NB * ND, Cpart, Lacc);
  finalize<<<576, 256, 0, stream>>>(Cpart, Lacc, out);
}

// Round 3
// 450.132 us; speedup vs baseline: 1.1810x; 1.1810x over previous
//
#include <hip/hip_runtime.h>
#include <hip/hip_bf16.h>
#include <math.h>

#define NB 32
#define NS 4096
#define ND 512
#define NU 128
#define RR 32
#define NCHUNK (NS / RR)   // 128
#define ASTR 520           // bf16 elems per LDS row (512 + 8 pad)

typedef __bf16 bf16x8 __attribute__((ext_vector_type(8)));
typedef unsigned short u16x8 __attribute__((ext_vector_type(8)));
typedef float f32x4 __attribute__((ext_vector_type(4)));
union FragCvt { u16x8 u; bf16x8 b; };

__device__ inline unsigned short f2bf(float x) {
  union { float f; unsigned u; } v; v.f = x;
  return (unsigned short)((v.u + 0x7FFFu + ((v.u >> 16) & 1u)) >> 16);
}
__device__ inline float bf2f(unsigned int bits16) {
  union { unsigned u; float f; } v; v.u = bits16 << 16;
  return v.f;
}
__device__ inline u16x8 pack8(float4 a, float4 b) {
  u16x8 r;
  r[0] = f2bf(a.x); r[1] = f2bf(a.y); r[2] = f2bf(a.z); r[3] = f2bf(a.w);
  r[4] = f2bf(b.x); r[5] = f2bf(b.y); r[6] = f2bf(b.z); r[7] = f2bf(b.w);
  return r;
}
// tanh(x) = 1 - 2/(e^{2x}+1); exact at +/-inf, ~1e-6 abs err (vs 4.9e-4 bf16 budget)
__device__ inline float fast_tanh(float x) {
  float ex = __expf(2.f * x);
  return 1.f - 2.f / (ex + 1.f);
}

// ---- prep: qb[b][u] = q@W1 + b1 + b2 ; w2t[u][d] = bf16(W2[d][u]) ----
__global__ void prep(const float* __restrict__ q, const float* __restrict__ W1,
                     const float* __restrict__ b1, const float* __restrict__ b2,
                     const float* __restrict__ W2,
                     float* __restrict__ qb, unsigned short* __restrict__ w2t) {
  if (blockIdx.x < 16) {
    int idx = blockIdx.x * 256 + threadIdx.x;    // 4096 = 32*128
    int b = idx >> 7, u = idx & 127;
    float s = b1[u] + b2[u];
    const float* qr = q + b * ND;
    #pragma unroll 8
    for (int d = 0; d < ND; ++d) s += qr[d] * W1[d * NU + u];
    qb[idx] = s;
  } else {
    int idx = (blockIdx.x - 16) * 256 + threadIdx.x;  // 65536 = 128*512
    int u = idx >> 9, d = idx & 511;
    w2t[idx] = f2bf(W2[d * NU + u]);
  }
}

// ---- fused: LDS-staged A, B from L2, barrier-free K-loop ----
__global__ __launch_bounds__(256, 4) void fused_attn(
    const float* __restrict__ values,
    const float* __restrict__ qb,            // [NB][NU]
    const unsigned short* __restrict__ w2t,  // [NU][ND] bf16 bits
    const float* __restrict__ V,             // [NU]
    const float* __restrict__ bvp,           // [1]
    float* __restrict__ wout,                // [NB][NS] unnormalized e^s
    float* __restrict__ Cpart,               // [NB*NCHUNK][ND] per-block partials
    float* __restrict__ Lacc)                // [NB] denom (zeroed)
{
  __shared__ unsigned short Alds[RR * ASTR];   // 33,280 B
  __shared__ float sbuf[4][32];
  __shared__ float wlds[RR];

  const int tid = threadIdx.x;
  const int b = blockIdx.x >> 7;
  const int chunk = blockIdx.x & 127;
  const int s0 = chunk * RR;
  const int wave = tid >> 6, lane = tid & 63;
  const int quad = lane >> 4, lidx = lane & 15;
  const int ng = wave;                         // 4 n-groups x 2 ntiles (32 u each)

  const float* vbase = values + ((size_t)b * NS + s0) * ND;

  // ---- stage A: 32x512 fp32 -> bf16 LDS, coalesced float8 per thread-iter ----
  #pragma unroll
  for (int i = 0; i < 8; ++i) {
    int p = tid + 256 * i;          // float8 index in [0, 2048)
    int row = p >> 6;               // 64 float8 per row
    int c8 = p & 63;
    const float* ap = vbase + row * ND + c8 * 8;
    float4 v0 = *(const float4*)ap;
    float4 v1 = *(const float4*)(ap + 4);
    *(u16x8*)(&Alds[row * ASTR + c8 * 8]) = pack8(v0, v1);
  }
  __syncthreads();

  // ---- K-loop: A from LDS, B from L2-resident w2t (16 full lines per load) ----
  f32x4 acc[2][2];
  #pragma unroll
  for (int mt = 0; mt < 2; ++mt)
    #pragma unroll
    for (int nt = 0; nt < 2; ++nt)
      acc[mt][nt] = (f32x4){0.f, 0.f, 0.f, 0.f};

  const unsigned short* b0p = w2t + (ng * 32 + lidx) * ND + quad * 8;
  const unsigned short* b1p = b0p + 16 * ND;
  const unsigned short* a0p = (const unsigned short*)&Alds[lidx * ASTR + quad * 8];
  const unsigned short* a1p = a0p + 16 * ASTR;

  #pragma unroll 4
  for (int kt = 0; kt < 16; ++kt) {
    FragCvt bf0, bf1, af0, af1;
    bf0.u = *(const u16x8*)(b0p + kt * 32);
    bf1.u = *(const u16x8*)(b1p + kt * 32);
    af0.u = *(const u16x8*)(a0p + kt * 32);
    af1.u = *(const u16x8*)(a1p + kt * 32);
    acc[0][0] = __builtin_amdgcn_mfma_f32_16x16x32_bf16(af0.b, bf0.b, acc[0][0], 0, 0, 0);
    acc[0][1] = __builtin_amdgcn_mfma_f32_16x16x32_bf16(af0.b, bf1.b, acc[0][1], 0, 0, 0);
    acc[1][0] = __builtin_amdgcn_mfma_f32_16x16x32_bf16(af1.b, bf0.b, acc[1][0], 0, 0, 0);
    acc[1][1] = __builtin_amdgcn_mfma_f32_16x16x32_bf16(af1.b, bf1.b, acc[1][1], 0, 0, 0);
  }

  // ---- epilogue: tanh + dot V; lane holds rows quad*4+r (per mtile), col ng*32+nt*16+lidx
  float part[2][4] = {{0.f,0.f,0.f,0.f},{0.f,0.f,0.f,0.f}};
  #pragma unroll
  for (int nt = 0; nt < 2; ++nt) {
    const int col = ng * 32 + nt * 16 + lidx;
    const float qv = qb[b * NU + col];
    const float vv = V[col];
    #pragma unroll
    for (int mt = 0; mt < 2; ++mt)
      #pragma unroll
      for (int r = 0; r < 4; ++r)
        part[mt][r] += fast_tanh(acc[mt][nt][r] + qv) * vv;
  }
  #pragma unroll
  for (int m = 1; m <= 8; m <<= 1)
    #pragma unroll
    for (int mt = 0; mt < 2; ++mt)
      #pragma unroll
      for (int r = 0; r < 4; ++r)
        part[mt][r] += __shfl_xor(part[mt][r], m, 64);
  if (lidx == 0) {
    #pragma unroll
    for (int mt = 0; mt < 2; ++mt)
      #pragma unroll
      for (int r = 0; r < 4; ++r)
        sbuf[ng][mt * 16 + quad * 4 + r] = part[mt][r];
  }
  __syncthreads();

  if (tid < 32) {
    float s = sbuf[0][tid] + sbuf[1][tid] + sbuf[2][tid] + sbuf[3][tid];
    float e = expf(s + *bvp);       // scores bounded by ||V||_1 ~ 9 -> no max pass
    wout[(size_t)b * NS + s0 + tid] = e;
    wlds[tid] = e;
    float es = e;
    #pragma unroll
    for (int m = 1; m <= 16; m <<= 1) es += __shfl_xor(es, m, 64);
    if (tid == 0) atomicAdd(Lacc + b, es);
  }
  __syncthreads();

  // ---- context partial from bf16 LDS: 2 cols/thread, conflict-free u32 reads ----
  const int d0 = tid * 2;
  float c0 = 0.f, c1 = 0.f;
  #pragma unroll 8
  for (int r = 0; r < RR; ++r) {
    float w = wlds[r];
    unsigned int pk = *(const unsigned int*)(&Alds[r * ASTR + d0]);
    c0 += w * bf2f(pk & 0xFFFFu);
    c1 += w * bf2f(pk >> 16);
  }
  float* cp = Cpart + (size_t)blockIdx.x * ND + d0;
  cp[0] = c0;
  cp[1] = c1;
}

// ---- finalize: tree-reduce context partials + normalize weights ----
__global__ void finalize(const float* __restrict__ Cpart, const float* __restrict__ Lacc,
                         float* __restrict__ out) {
  int idx = blockIdx.x * 256 + threadIdx.x;   // 147456 total
  if (idx < NB * ND) {
    int b = idx >> 9, d = idx & 511;
    const float* p = Cpart + (size_t)b * NCHUNK * ND + d;
    float a0 = 0.f, a1 = 0.f, a2 = 0.f, a3 = 0.f;
    #pragma unroll 4
    for (int c = 0; c < NCHUNK; c += 4) {
      a0 += p[(size_t)(c + 0) * ND];
      a1 += p[(size_t)(c + 1) * ND];
      a2 += p[(size_t)(c + 2) * ND];
      a3 += p[(size_t)(c + 3) * ND];
    }
    out[idx] = (a0 + a1 + a2 + a3) / Lacc[b];
  } else {
    int j = idx - NB * ND;
    int b = j >> 12;
    out[idx] = out[idx] / Lacc[b];
  }
}

extern "C" void kernel_launch(void* const* d_in, const int* in_sizes, int n_in,
                              void* d_out, int out_size, void* d_ws, size_t ws_size,
                              hipStream_t stream) {
  const float* query  = (const float*)d_in[0];
  const float* values = (const float*)d_in[1];
  const float* W1     = (const float*)d_in[2];
  const float* b1     = (const float*)d_in[3];
  const float* W2     = (const float*)d_in[4];
  const float* b2     = (const float*)d_in[5];
  const float* V      = (const float*)d_in[6];
  const float* bv     = (const float*)d_in[7];
  float* out = (float*)d_out;

  char* ws = (char*)d_ws;
  float* Cpart = (float*)ws;                                   // 4096*512*4 = 8 MB
  float* Lacc  = (float*)(ws + 8388608);                       // 128 B (512 reserved)
  float* qbuf  = (float*)(ws + 8389120);                       // 16 KB
  unsigned short* w2t = (unsigned short*)(ws + 8405504);       // 128 KB

  hipMemsetAsync(Lacc, 0, 512, stream);

  prep<<<272, 256, 0, stream>>>(query, W1, b1, b2, W2, qbuf, w2t);
  fused_attn<<<NB * NCHUNK, 256, 0, stream>>>(values, qbuf, w2t, V, bv,
                                              out + NB * ND, Cpart, Lacc);
  finalize<<<576, 256, 0, stream>>>(Cpart, Lacc, out);
}